// Round 2
// baseline (328.631 us; speedup 1.0000x reference)
//
#include <hip/hip_runtime.h>
#include <hip/hip_bf16.h>
#include <math.h>

#define TT 2048
#define BB 8
#define DD 128
#define HH 4
#define BT (BB*TT)
#define BH (BB*HH)
#define SCALE 0.1767766952966369f
#define S2LOG (SCALE * 1.4426950408889634f)   // scale * log2(e)

typedef __attribute__((ext_vector_type(8))) short short8;
typedef __attribute__((ext_vector_type(4))) short short4v;
typedef __attribute__((ext_vector_type(4))) float f32x4;
typedef __hip_bfloat16 bf16;

#define MFMA16(a,b,c) __builtin_amdgcn_mfma_f32_16x16x32_bf16(a,b,c,0,0,0)

static __device__ inline short8 ldg8(const bf16* p) {
  return *reinterpret_cast<const short8*>(p);
}
static __device__ inline short4v ldg4(const bf16* p) {
  return *reinterpret_cast<const short4v*>(p);
}
static __device__ inline short f2bs(float x) {
  bf16 h = __float2bfloat16(x);
  return *reinterpret_cast<short*>(&h);
}
// load 8 contiguous f32 from global, convert to bf16 A/B-fragment
static __device__ inline short8 ldcvt8(const float* p) {
  f32x4 f0 = *reinterpret_cast<const f32x4*>(p);
  f32x4 f1 = *reinterpret_cast<const f32x4*>(p + 4);
  short8 r;
  #pragma unroll
  for (int i = 0; i < 4; ++i) { r[i] = f2bs(f0[i]); r[4+i] = f2bs(f1[i]); }
  return r;
}

// ---------------- Kernel 1: MFMA projections (unchanged) ----------------
__global__ __launch_bounds__(256) void proj_kernel(
    const float* __restrict__ lob, const float* __restrict__ hawkes,
    const float* __restrict__ Wp, const float* __restrict__ bp,
    const float* __restrict__ Win, const float* __restrict__ binp,
    bf16* __restrict__ qg, bf16* __restrict__ kg, bf16* __restrict__ vtg) {
  __shared__ bf16 hT[32*136];
  __shared__ bf16 vT[128*40];
  int tid = threadIdx.x;
  int wave = tid >> 6, lane = tid & 63;
  int lr = lane & 15, lq = lane >> 4;
  int r0 = blockIdx.x * 32;
  int b  = r0 >> 11, t0 = r0 & 2047;
  f32x4 z = {0.f,0.f,0.f,0.f};

  short8 alob[2][4], ahk[2];
  #pragma unroll
  for (int mt = 0; mt < 2; ++mt) {
    const float* lp = lob + (size_t)(r0 + mt*16 + lr)*128;
    #pragma unroll
    for (int kt = 0; kt < 4; ++kt) alob[mt][kt] = ldcvt8(lp + kt*32 + lq*8);
    ahk[mt] = ldcvt8(hawkes + (size_t)(r0 + mt*16 + lr)*32 + lq*8);
  }

  for (int nt = wave; nt < 8; nt += 4) {
    int cn = nt*16;
    short8 bfrag = ldcvt8(Wp + (size_t)(cn + lr)*32 + lq*8);
    float bias = bp[cn + lr];
    #pragma unroll
    for (int mt = 0; mt < 2; ++mt) {
      f32x4 c = MFMA16(ahk[mt], bfrag, z);
      #pragma unroll
      for (int r = 0; r < 4; ++r)
        hT[(mt*16 + lq*4 + r)*136 + cn + lr] = __float2bfloat16(c[r] + bias);
    }
  }
  __syncthreads();

  short8 ah[2][4];
  #pragma unroll
  for (int mt = 0; mt < 2; ++mt)
    #pragma unroll
    for (int kt = 0; kt < 4; ++kt)
      ah[mt][kt] = *reinterpret_cast<const short8*>(&hT[(mt*16 + lr)*136 + kt*32 + lq*8]);

  for (int nt = wave; nt < 24; nt += 4) {
    int which = nt >> 3;
    int c = (nt & 7)*16 + lr;
    const float* wrow = Win + (size_t)(which*128 + c)*128;
    float bias = binp[which*128 + c];
    f32x4 acc0 = z, acc1 = z;
    #pragma unroll
    for (int kt = 0; kt < 4; ++kt) {
      short8 bfrag = ldcvt8(wrow + kt*32 + lq*8);
      if (which == 0) {
        acc0 = MFMA16(alob[0][kt], bfrag, acc0);
        acc1 = MFMA16(alob[1][kt], bfrag, acc1);
      } else {
        acc0 = MFMA16(ah[0][kt], bfrag, acc0);
        acc1 = MFMA16(ah[1][kt], bfrag, acc1);
      }
    }
    int head = c >> 5, dd = c & 31;
    #pragma unroll
    for (int mt = 0; mt < 2; ++mt) {
      f32x4 acc = mt ? acc1 : acc0;
      #pragma unroll
      for (int r = 0; r < 4; ++r) {
        int row = mt*16 + lq*4 + r;
        float val = acc[r] + bias;
        if (which == 0)
          qg[((size_t)(b*HH + head)*TT + t0 + row)*32 + dd] = __float2bfloat16(val);
        else if (which == 1)
          kg[((size_t)(b*HH + head)*TT + t0 + row)*32 + dd] = __float2bfloat16(val);
        else
          vT[c*40 + row] = __float2bfloat16(val);
      }
    }
  }
  __syncthreads();

  {
    int dd = tid >> 1, half = tid & 1;
    int bh = b*HH + (dd >> 5);
    short8 s0 = *reinterpret_cast<const short8*>(&vT[dd*40 + half*16]);
    short8 s1 = *reinterpret_cast<const short8*>(&vT[dd*40 + half*16 + 8]);
    bf16* dst = vtg + ((size_t)bh*32 + (dd & 31))*TT + t0 + half*16;
    *reinterpret_cast<short8*>(dst) = s0;
    *reinterpret_cast<short8*>(dst + 8) = s1;
  }
}

// ---------------- Kernel 2: fused attention, k-split waves ----------------
// Block = (b, qt): 32 q-rows. 4 waves; wave w owns k-subtiles s === w (mod 4),
// for ALL 4 heads. Cross-head attn_w mean is an in-register sum -> f32x4
// straight to global; NO P LDS, NO in-loop barriers. PV uses the permuted-k
// register trick (two 16-k subtiles -> one 32-k MFMA). ctx partials (k-split)
// are reduced across waves through LDS at the end, written bf16.
__global__ __launch_bounds__(256) void attn_kernel(const bf16* __restrict__ qg,
    const bf16* __restrict__ kg, const bf16* __restrict__ vtg,
    float* __restrict__ attn_out, bf16* __restrict__ ctxg) {
  // XCD swizzle: 512 blocks = 8 XCDs x 64; each XCD owns one batch b.
  int wgid = (blockIdx.x & 7)*64 + (blockIdx.x >> 3);
  int b = wgid >> 6, qt = wgid & 63;
  int wave = threadIdx.x >> 6, lane = threadIdx.x & 63;
  int lr = lane & 15, lq = lane >> 4;
  __shared__ float sRed[4][16*132];      // 33.8 KB; first 512 floats reused as sdl
  float* sdl = &sRed[0][0];
  const bf16* qb = qg + ((size_t)(b*HH)*TT + (size_t)qt*32)*32;
  const bf16* kb = kg + (size_t)(b*HH)*TT*32;
  const bf16* vb = vtg + (size_t)(b*HH)*32*TT;
  f32x4 z = {0.f,0.f,0.f,0.f};

  // Q B-frags, all heads: lane holds Q[q=lr(+16m)][d=lq*8+j]
  short8 aq[4][2];
  #pragma unroll
  for (int h = 0; h < 4; ++h)
    #pragma unroll
    for (int m = 0; m < 2; ++m)
      aq[h][m] = ldg8(qb + (size_t)h*TT*32 + (m*16 + lr)*32 + lq*8);

  // ---- pass 1: denominators. S^T = MFMA(K,Q): lane holds S[q=lr][k=s*16+lq*4+r]
  float rs[4][2] = {{0.f,0.f},{0.f,0.f},{0.f,0.f},{0.f,0.f}};
  for (int i = 0; i < 32; ++i) {
    int s = wave + i*4;
    #pragma unroll
    for (int h = 0; h < 4; ++h) {
      short8 kf = ldg8(kb + (size_t)h*TT*32 + (s*16 + lr)*32 + lq*8);
      #pragma unroll
      for (int m = 0; m < 2; ++m) {
        f32x4 sv = MFMA16(kf, aq[h][m], z);
        #pragma unroll
        for (int r = 0; r < 4; ++r) rs[h][m] += exp2f(sv[r]*S2LOG);
      }
    }
  }
  #pragma unroll
  for (int h = 0; h < 4; ++h)
    #pragma unroll
    for (int m = 0; m < 2; ++m) {
      rs[h][m] += __shfl_xor(rs[h][m], 16, 64);
      rs[h][m] += __shfl_xor(rs[h][m], 32, 64);
    }
  if (lq == 0) {
    #pragma unroll
    for (int h = 0; h < 4; ++h)
      #pragma unroll
      for (int m = 0; m < 2; ++m)
        sdl[wave*128 + h*32 + m*16 + lr] = rs[h][m];
  }
  __syncthreads();
  float lb[4][2];
  #pragma unroll
  for (int h = 0; h < 4; ++h)
    #pragma unroll
    for (int m = 0; m < 2; ++m) {
      float t = sdl[0*128 + h*32 + m*16 + lr] + sdl[1*128 + h*32 + m*16 + lr]
              + sdl[2*128 + h*32 + m*16 + lr] + sdl[3*128 + h*32 + m*16 + lr];
      lb[h][m] = -log2f(t);
    }
  __syncthreads();

  // ---- pass 2: normalized P -> attn_w (in-register head sum) + PV
  f32x4 acc[4][2][2];   // [h][m][dt]: q = m*16+lq*4+r, d = h*32+dt*16+lr
  #pragma unroll
  for (int h = 0; h < 4; ++h)
    #pragma unroll
    for (int m = 0; m < 2; ++m)
      #pragma unroll
      for (int dt = 0; dt < 2; ++dt) acc[h][m][dt] = z;

  float* awr = attn_out + (size_t)(b*TT + qt*32)*TT;
  for (int i = 0; i < 16; ++i) {
    int sA = wave + i*8, sB = sA + 4;
    f32x4 awA0 = z, awA1 = z, awB0 = z, awB1 = z;
    #pragma unroll
    for (int h = 0; h < 4; ++h) {
      const bf16* kph = kb + (size_t)h*TT*32;
      short8 kfA = ldg8(kph + (sA*16 + lr)*32 + lq*8);
      short8 kfB = ldg8(kph + (sB*16 + lr)*32 + lq*8);
      short8 apm[2];
      #pragma unroll
      for (int m = 0; m < 2; ++m) {
        f32x4 svA = MFMA16(kfA, aq[h][m], z);
        f32x4 svB = MFMA16(kfB, aq[h][m], z);
        f32x4 pA, pB;
        #pragma unroll
        for (int r = 0; r < 4; ++r) {
          pA[r] = exp2f(fmaf(svA[r], S2LOG, lb[h][m]));
          pB[r] = exp2f(fmaf(svB[r], S2LOG, lb[h][m]));
        }
        if (m == 0) { awA0 += pA; awB0 += pB; } else { awA1 += pA; awB1 += pB; }
        short8 ap;
        #pragma unroll
        for (int r = 0; r < 4; ++r) { ap[r] = f2bs(pA[r]); ap[4+r] = f2bs(pB[r]); }
        apm[m] = ap;
      }
      const bf16* vph = vb + (size_t)h*32*TT;
      #pragma unroll
      for (int dt = 0; dt < 2; ++dt) {
        const bf16* vp = vph + (size_t)(dt*16 + lr)*TT;
        short4v lo = ldg4(vp + sA*16 + lq*4);
        short4v hi = ldg4(vp + sB*16 + lq*4);
        short8 vf;
        #pragma unroll
        for (int j = 0; j < 4; ++j) { vf[j] = lo[j]; vf[4+j] = hi[j]; }
        acc[h][0][dt] = MFMA16(apm[0], vf, acc[h][0][dt]);
        acc[h][1][dt] = MFMA16(apm[1], vf, acc[h][1][dt]);
      }
    }
    *reinterpret_cast<f32x4*>(awr + (size_t)lr*TT      + sA*16 + lq*4) = awA0 * 0.25f;
    *reinterpret_cast<f32x4*>(awr + (size_t)lr*TT      + sB*16 + lq*4) = awB0 * 0.25f;
    *reinterpret_cast<f32x4*>(awr + (size_t)(16+lr)*TT + sA*16 + lq*4) = awA1 * 0.25f;
    *reinterpret_cast<f32x4*>(awr + (size_t)(16+lr)*TT + sB*16 + lq*4) = awB1 * 0.25f;
  }

  // ---- cross-wave ctx reduction (k-split partials), bf16 out
  bf16* cbase = ctxg + (size_t)(b*TT + qt*32)*128;
  #pragma unroll
  for (int m = 0; m < 2; ++m) {
    #pragma unroll
    for (int h = 0; h < 4; ++h)
      #pragma unroll
      for (int dt = 0; dt < 2; ++dt)
        #pragma unroll
        for (int r = 0; r < 4; ++r)
          sRed[wave][(lq*4 + r)*132 + h*32 + dt*16 + lr] = acc[h][m][dt][r];
    __syncthreads();
    {
      int t = threadIdx.x;
      int q = t >> 4, d0 = (t & 15)*8;
      float v[8];
      #pragma unroll
      for (int j = 0; j < 8; ++j)
        v[j] = sRed[0][q*132 + d0 + j] + sRed[1][q*132 + d0 + j]
             + sRed[2][q*132 + d0 + j] + sRed[3][q*132 + d0 + j];
      short8 o;
      #pragma unroll
      for (int j = 0; j < 8; ++j) o[j] = f2bs(v[j]);
      *reinterpret_cast<short8*>(cbase + (size_t)(m*16 + q)*128 + d0) = o;
    }
    __syncthreads();
  }
}

// ---------------- Kernel 3: MFMA out-proj + residual + LayerNorm ------------
__global__ __launch_bounds__(256) void outln_kernel(const bf16* __restrict__ ctxg,
    const float* __restrict__ lob, const float* __restrict__ Wo,
    const float* __restrict__ bo, const float* __restrict__ gamma,
    const float* __restrict__ beta, float* __restrict__ outg) {
  __shared__ float sX[32*132];
  __shared__ float sPar[256];   // gamma, beta
  int tid = threadIdx.x, wave = tid >> 6, lane = tid & 63;
  int lr = lane & 15, lq = lane >> 4;
  int r0 = blockIdx.x * 32;
  if (tid < 128) { sPar[tid] = gamma[tid]; sPar[128+tid] = beta[tid]; }
  f32x4 z = {0.f,0.f,0.f,0.f};
  // ctx A-frags (bf16)
  short8 actx[2][4];
  #pragma unroll
  for (int mt = 0; mt < 2; ++mt)
    #pragma unroll
    for (int kt = 0; kt < 4; ++kt)
      actx[mt][kt] = ldg8(ctxg + (size_t)(r0 + mt*16 + lr)*128 + kt*32 + lq*8);
  // out = ctx @ Wo^T + bo + lob  -> sX
  for (int nt = wave; nt < 8; nt += 4) {
    f32x4 acc0 = z, acc1 = z;
    #pragma unroll
    for (int kt = 0; kt < 4; ++kt) {
      short8 bfrag = ldcvt8(Wo + (size_t)(nt*16 + lr)*128 + kt*32 + lq*8);
      acc0 = MFMA16(actx[0][kt], bfrag, acc0);
      acc1 = MFMA16(actx[1][kt], bfrag, acc1);
    }
    int d = nt*16 + lr;
    float bias = bo[d];
    #pragma unroll
    for (int mt = 0; mt < 2; ++mt) {
      f32x4 acc = mt ? acc1 : acc0;
      #pragma unroll
      for (int r = 0; r < 4; ++r) {
        int row = mt*16 + lq*4 + r;
        sX[row*132 + d] = acc[r] + bias + lob[(size_t)(r0 + row)*128 + d];
      }
    }
  }
  __syncthreads();
  // LayerNorm: 8 threads per row (consecutive lanes), 16 f32 each
  {
    int row = tid >> 3, j = tid & 7;
    const float* xp = &sX[row*132 + j*16];
    f32x4 x[4];
    #pragma unroll
    for (int v = 0; v < 4; ++v) x[v] = *reinterpret_cast<const f32x4*>(xp + v*4);
    float sum = 0.f, sq = 0.f;
    #pragma unroll
    for (int v = 0; v < 4; ++v)
      #pragma unroll
      for (int e = 0; e < 4; ++e) { sum += x[v][e]; sq += x[v][e]*x[v][e]; }
    #pragma unroll
    for (int mdx = 1; mdx < 8; mdx <<= 1) {
      sum += __shfl_xor(sum, mdx, 64);
      sq  += __shfl_xor(sq,  mdx, 64);
    }
    float mu = sum * (1.0f/128.0f);
    float rstd = rsqrtf(sq*(1.0f/128.0f) - mu*mu + 1e-5f);
    float* op = outg + (size_t)(r0 + row)*128 + j*16;
    #pragma unroll
    for (int v = 0; v < 4; ++v) {
      f32x4 o;
      #pragma unroll
      for (int e = 0; e < 4; ++e) {
        int d = j*16 + v*4 + e;
        o[e] = (x[v][e] - mu)*rstd*sPar[d] + sPar[128+d];
      }
      *reinterpret_cast<f32x4*>(op + v*4) = o;
    }
  }
}

extern "C" void kernel_launch(void* const* d_in, const int* in_sizes, int n_in,
                              void* d_out, int out_size, void* d_ws, size_t ws_size,
                              hipStream_t stream) {
  const float* lob    = (const float*)d_in[0];
  const float* hawkes = (const float*)d_in[1];
  const float* Wp     = (const float*)d_in[2];
  const float* bp     = (const float*)d_in[3];
  const float* Win    = (const float*)d_in[4];
  const float* binp   = (const float*)d_in[5];
  const float* Wo     = (const float*)d_in[6];
  const float* bo     = (const float*)d_in[7];
  const float* gamma  = (const float*)d_in[8];
  const float* beta   = (const float*)d_in[9];
  float* outg = (float*)d_out;
  float* attn_out = outg + (size_t)BT*128;   // out (B,T,128) then attn_w (B,T,T)

  char* ws = (char*)d_ws;
  bf16*  qg   = (bf16*)(ws);                                   // 4 MB
  bf16*  kg   = (bf16*)(ws + (size_t)4*1024*1024);             // 4 MB
  bf16*  vtg  = (bf16*)(ws + (size_t)8*1024*1024);             // 4 MB (B,H,32,T)
  bf16*  ctxg = (bf16*)(ws + (size_t)12*1024*1024);            // 4 MB (B,T,128)

  proj_kernel<<<BT/32, 256, 0, stream>>>(lob, hawkes, Wp, bp, Win, binp, qg, kg, vtg);
  attn_kernel<<<BB*(TT/32), 256, 0, stream>>>(qg, kg, vtg, attn_out, ctxg);
  outln_kernel<<<512, 256, 0, stream>>>(ctxg, lob, Wo, bo, gamma, beta, outg);
}